// Round 5
// baseline (2338.300 us; speedup 1.0000x reference)
//
#include <hip/hip_runtime.h>

#define N_NODES 50000
#define HIDDEN  64
#define N_EDGES 1200000

#define BSHIFT 7                      // 128 nodes per bucket
#define BUKSZ  128
#define NBUK   391                    // ceil(50000/128)
#define GBIN   192                    // scatter blocks -> 16-edge runs (64B packed)
#define PAD2   4096                   // padded capacity per bucket (avg 3069, ~18 sigma)
#define AGG_THREADS 512

__device__ __forceinline__ float bcastf(float v, int k) {
    return __int_as_float(__builtin_amdgcn_readlane(__float_as_int(v), k));
}

// f32 -> bf16 (RNE) as ushort
__device__ __forceinline__ unsigned short f2bf(float x) {
    unsigned u = __float_as_uint(x);
    u += 0x7fffu + ((u >> 16) & 1u);
    return (unsigned short)(u >> 16);
}

// ---------------- bucketed pair build (2 dispatches, no sort) ----------------

__global__ __launch_bounds__(512) void init_kernel(int* __restrict__ cursor) {
    int tid = threadIdx.x;
    if (tid < NBUK) cursor[tid] = tid * PAD2;
}

// per-block LDS hist -> one global reservation per (block,bucket) -> LDS-cursor scatter
// of packed (src | dstLocal<<16) ints
__global__ __launch_bounds__(256) void scatter_fused_kernel(const int* __restrict__ ei,
                                                            int* __restrict__ cursor,
                                                            int* __restrict__ tmp, int E) {
    __shared__ int h[NBUK];
    __shared__ int cur[NBUK];
    int tid = threadIdx.x;
    for (int b = tid; b < NBUK; b += 256) h[b] = 0;
    __syncthreads();
    for (int e = blockIdx.x * 256 + tid; e < E; e += GBIN * 256)
        atomicAdd(&h[ei[E + e] >> BSHIFT], 1);
    __syncthreads();
    for (int b = tid; b < NBUK; b += 256) cur[b] = atomicAdd(&cursor[b], h[b]);
    __syncthreads();
    for (int e = blockIdx.x * 256 + tid; e < E; e += GBIN * 256) {
        int src = ei[e];
        int dst = ei[E + e];
        int p = atomicAdd(&cur[dst >> BSHIFT], 1);
        tmp[p] = src | ((dst & (BUKSZ - 1)) << 16);
    }
}

// ---------------- dense GEMMs: t(bf16) = h@Wnbr ; u = h@Wself + b ----------------
__global__ __launch_bounds__(256) void gemm2_kernel(const float* __restrict__ h,
                                                    const float* __restrict__ Wnbr,
                                                    const float* __restrict__ Wself,
                                                    const float* __restrict__ bias,
                                                    unsigned short* __restrict__ tbf,
                                                    float* __restrict__ u, int n) {
    int lane = threadIdx.x & 63;
    float wn[64], ws[64];
#pragma unroll
    for (int k = 0; k < 64; ++k) {
        wn[k] = Wnbr[k * 64 + lane];
        ws[k] = Wself[k * 64 + lane];
    }
    float bv = bias[lane];
    int wave = (blockIdx.x * 256 + threadIdx.x) >> 6;
    int nwaves = gridDim.x * 4;
    if (wave == 0) tbf[(size_t)n * 64 + lane] = 0;   // zero row n (padding target)
    for (int i = wave; i < n; i += nwaves) {
        float hv = h[i * 64 + lane];
        float tacc = 0.f, uacc = bv;
#pragma unroll
        for (int k = 0; k < 64; ++k) {
            float hk = bcastf(hv, k);
            tacc = fmaf(hk, wn[k], tacc);
            uacc = fmaf(hk, ws[k], uacc);
        }
        tbf[(size_t)i * 64 + lane] = f2bf(tacc);
        u[(size_t)i * 64 + lane] = uacc;
    }
}

// ---------------- LDS-accumulate aggregation + epilogue ----------------
// one block per 128-node bucket; acc[128][65] f32 in LDS; ds_add_f32 has no return
// value -> no dependency chain -> deep MLP on the t-row gathers.
__global__ __launch_bounds__(AGG_THREADS) void agg_kernel(const unsigned short* __restrict__ tbf,
                                                          const float* __restrict__ u,
                                                          const int* __restrict__ cursor,
                                                          const int* __restrict__ tmp,
                                                          float* __restrict__ out,
                                                          int n, int use_mean) {
    __shared__ float acc[BUKSZ * 65];
    __shared__ int deg[BUKSZ];
    int tid = threadIdx.x;
    for (int i = tid; i < BUKSZ * 65; i += AGG_THREADS) acc[i] = 0.f;
    if (tid < BUKSZ) deg[tid] = 0;
    __syncthreads();

    int b = blockIdx.x;
    int base = b * PAD2;
    int count = cursor[b] - base;
    int lane = tid & 63, g = lane >> 4, q = lane & 15;
    int w = tid >> 6;
    const int PADV = 50000 | ((BUKSZ - 1) << 16);   // src=zero row, dl=127 (adds 0.0)

    for (int c = w * 64; c < count; c += (AGG_THREADS / 64) * 64) {
        int v = (c + lane < count) ? tmp[base + c + lane] : PADV;
#pragma unroll
        for (int j = 0; j < 64; j += 4) {
            int p = __shfl(v, j + g);
            int s = p & 0xFFFF;
            int dl = p >> 16;
            const uint2 wv = *(const uint2*)(tbf + (size_t)s * 64 + q * 4);
            float* ap = &acc[dl * 65 + q * 4];
            atomicAdd(ap + 0, __uint_as_float(wv.x << 16));
            atomicAdd(ap + 1, __uint_as_float(wv.x & 0xffff0000u));
            atomicAdd(ap + 2, __uint_as_float(wv.y << 16));
            atomicAdd(ap + 3, __uint_as_float(wv.y & 0xffff0000u));
            if (use_mean && q == 0 && (c + j + g) < count) atomicAdd(&deg[dl], 1);
        }
    }
    __syncthreads();

    int node_base = b << BSHIFT;
#pragma unroll
    for (int r = 0; r < (BUKSZ * 16) / AGG_THREADS; ++r) {   // 4
        int slot = r * AGG_THREADS + tid;
        int nl = slot >> 4, qq = slot & 15;
        int node = node_base + nl;
        if (node < n) {
            const float4 uv = *(const float4*)(u + (size_t)node * 64 + qq * 4);
            float sc = use_mean ? 1.f / fmaxf((float)deg[nl], 1.f) : 1.f;
            const float* ap = &acc[nl * 65 + qq * 4];
            float4 o;
            o.x = fmaxf(uv.x + ap[0] * sc, 0.f);
            o.y = fmaxf(uv.y + ap[1] * sc, 0.f);
            o.z = fmaxf(uv.z + ap[2] * sc, 0.f);
            o.w = fmaxf(uv.w + ap[3] * sc, 0.f);
            *(float4*)(out + (size_t)node * 64 + qq * 4) = o;
        }
    }
}

// ---------------- launch ----------------

extern "C" void kernel_launch(void* const* d_in, const int* in_sizes, int n_in,
                              void* d_out, int out_size, void* d_ws, size_t ws_size,
                              hipStream_t stream) {
    const float* x      = (const float*)d_in[0];
    const int*   ei     = (const int*)d_in[1];   // [2, E] int32
    const float* Wrel1  = (const float*)d_in[2];
    const float* Wroot1 = (const float*)d_in[3];
    const float* b1     = (const float*)d_in[4];
    const float* Wself2 = (const float*)d_in[5];
    const float* Wnbr2  = (const float*)d_in[6];
    const float* b2     = (const float*)d_in[7];
    const float* Wself3 = (const float*)d_in[8];
    const float* Wnbr3  = (const float*)d_in[9];
    const float* b3     = (const float*)d_in[10];
    const float* Wself4 = (const float*)d_in[11];
    const float* Wnbr4  = (const float*)d_in[12];
    const float* b4     = (const float*)d_in[13];

    const int N = N_NODES, E = N_EDGES;

    auto align = [](size_t o) { return (o + 255) & ~(size_t)255; };
    char* base = (char*)d_ws;
    size_t off = 0;
    int* cursor = (int*)(base + off); off = align(off + (size_t)NBUK * 4);
    int* tmp    = (int*)(base + off); off = align(off + (size_t)NBUK * PAD2 * 4);
    unsigned short* tbf = (unsigned short*)(base + off); off = align(off + (size_t)(N + 1) * 64 * 2);
    float* u  = (float*)(base + off); off = align(off + (size_t)N * 64 * 4);
    float* h1 = (float*)(base + off); off = align(off + (size_t)N * 64 * 4);

    float* out1 = (float*)d_out;                      // x_1
    float* out2 = (float*)d_out + (size_t)N * 64;     // x_2

    // ---- build: 2 dispatches ----
    init_kernel<<<1, 512, 0, stream>>>(cursor);
    scatter_fused_kernel<<<GBIN, 256, 0, stream>>>(ei, cursor, tmp, E);

    const int GB = 768;            // gemm blocks (3072 waves)

    // Layer 1 (RGCN): u = x@W_root1 + b1 ; t = x@W_rel1 ; mean aggregate
    gemm2_kernel<<<GB, 256, 0, stream>>>(x, Wrel1, Wroot1, b1, tbf, u, N);
    agg_kernel<<<NBUK, AGG_THREADS, 0, stream>>>(tbf, u, cursor, tmp, h1, N, 1);
    // Layer 2 (GraphConv) -> x_1
    gemm2_kernel<<<GB, 256, 0, stream>>>(h1, Wnbr2, Wself2, b2, tbf, u, N);
    agg_kernel<<<NBUK, AGG_THREADS, 0, stream>>>(tbf, u, cursor, tmp, out1, N, 0);
    // Layer 3
    gemm2_kernel<<<GB, 256, 0, stream>>>(out1, Wnbr3, Wself3, b3, tbf, u, N);
    agg_kernel<<<NBUK, AGG_THREADS, 0, stream>>>(tbf, u, cursor, tmp, h1, N, 0);
    // Layer 4 -> x_2
    gemm2_kernel<<<GB, 256, 0, stream>>>(h1, Wnbr4, Wself4, b4, tbf, u, N);
    agg_kernel<<<NBUK, AGG_THREADS, 0, stream>>>(tbf, u, cursor, tmp, out2, N, 0);
}

// Round 6
// 336.107 us; speedup vs baseline: 6.9570x; 6.9570x over previous
//
#include <hip/hip_runtime.h>

#define N_NODES 50000
#define HIDDEN  64
#define N_EDGES 1200000

#define BSHIFT 7                      // 128 nodes per bucket
#define BUKSZ  128
#define NBUK   391                    // ceil(50000/128)
#define GBIN   256                    // scatter blocks
#define PAD2   4096                   // padded capacity per bucket (avg 3069, ~18 sigma)

__device__ __forceinline__ float bcastf(float v, int k) {
    return __int_as_float(__builtin_amdgcn_readlane(__float_as_int(v), k));
}

// f32 -> bf16 (RNE) as ushort
__device__ __forceinline__ unsigned short f2bf(float x) {
    unsigned u = __float_as_uint(x);
    u += 0x7fffu + ((u >> 16) & 1u);
    return (unsigned short)(u >> 16);
}

__device__ __forceinline__ float bfl(unsigned w) { return __uint_as_float(w << 16); }
__device__ __forceinline__ float bfh(unsigned w) { return __uint_as_float(w & 0xffff0000u); }

// ---------------- bucketed CSR build ----------------

__global__ __launch_bounds__(512) void init_kernel(int* __restrict__ cursor) {
    int tid = threadIdx.x;
    if (tid < NBUK) cursor[tid] = tid * PAD2;
}

// per-block LDS hist -> one global reservation per (block,bucket) -> LDS-cursor scatter
// of packed (src | dstLocal<<16) ints
__global__ __launch_bounds__(256) void scatter_fused_kernel(const int* __restrict__ ei,
                                                            int* __restrict__ cursor,
                                                            int* __restrict__ tmp, int E) {
    __shared__ int h[NBUK];
    __shared__ int cur[NBUK];
    int tid = threadIdx.x;
    for (int b = tid; b < NBUK; b += 256) h[b] = 0;
    __syncthreads();
    for (int e = blockIdx.x * 256 + tid; e < E; e += GBIN * 256)
        atomicAdd(&h[ei[E + e] >> BSHIFT], 1);
    __syncthreads();
    for (int b = tid; b < NBUK; b += 256) cur[b] = atomicAdd(&cursor[b], h[b]);
    __syncthreads();
    for (int e = blockIdx.x * 256 + tid; e < E; e += GBIN * 256) {
        int src = ei[e];
        int dst = ei[E + e];
        int p = atomicAdd(&cur[dst >> BSHIFT], 1);
        tmp[p] = src | ((dst & (BUKSZ - 1)) << 16);
    }
}

// one 512-thread block per bucket: LDS hist(128) -> scan -> counting sort -> csr (ushort)
__global__ __launch_bounds__(512) void bucketize_kernel(const int* __restrict__ tmp,
                                                        const int* __restrict__ cursor,
                                                        int2* __restrict__ row_info,
                                                        unsigned short* __restrict__ csr,
                                                        int n) {
    __shared__ int hist[BUKSZ];
    __shared__ int cur[BUKSZ];
    __shared__ unsigned short stage[PAD2];
    int b = blockIdx.x, tid = threadIdx.x;
    int base = b * PAD2;
    int count = cursor[b] - base;
    int node_base = b << BSHIFT;

    if (tid < BUKSZ) hist[tid] = 0;
    __syncthreads();
    for (int i = tid; i < count; i += 512)
        atomicAdd(&hist[tmp[base + i] >> 16], 1);
    __syncthreads();
    int v = (tid < BUKSZ) ? hist[tid] : 0;
#pragma unroll
    for (int o = 1; o < BUKSZ; o <<= 1) {   // Hillis-Steele inclusive scan (tid<128)
        __syncthreads();
        int y = (tid >= o && tid < BUKSZ) ? hist[tid - o] : 0;
        __syncthreads();
        if (tid < BUKSZ) hist[tid] += y;
    }
    __syncthreads();
    if (tid < BUKSZ) {
        int excl = hist[tid] - v;
        cur[tid] = excl;
        int node = node_base + tid;
        if (node < n) row_info[node] = make_int2(base + excl, v);
    }
    __syncthreads();
    for (int i = tid; i < count; i += 512) {
        int p = tmp[base + i];
        int slot = atomicAdd(&cur[p >> 16], 1);
        stage[slot] = (unsigned short)(p & 0xFFFF);
    }
    __syncthreads();
    for (int i = tid; i < count; i += 512)
        csr[base + i] = stage[i];
}

// ---------------- dense GEMMs: t(bf16) = h@Wnbr ; u = h@Wself + b ----------------
__global__ __launch_bounds__(256) void gemm2_kernel(const float* __restrict__ h,
                                                    const float* __restrict__ Wnbr,
                                                    const float* __restrict__ Wself,
                                                    const float* __restrict__ bias,
                                                    unsigned short* __restrict__ tbf,
                                                    float* __restrict__ u, int n) {
    int lane = threadIdx.x & 63;
    float wn[64], ws[64];
#pragma unroll
    for (int k = 0; k < 64; ++k) {
        wn[k] = Wnbr[k * 64 + lane];
        ws[k] = Wself[k * 64 + lane];
    }
    float bv = bias[lane];
    int wave = (blockIdx.x * 256 + threadIdx.x) >> 6;
    int nwaves = gridDim.x * 4;
    if (wave == 0) tbf[(size_t)n * 64 + lane] = 0;   // zero row n (padding target)
    for (int i = wave; i < n; i += nwaves) {
        float hv = h[i * 64 + lane];
        float tacc = 0.f, uacc = bv;
#pragma unroll
        for (int k = 0; k < 64; ++k) {
            float hk = bcastf(hv, k);
            tacc = fmaf(hk, wn[k], tacc);
            uacc = fmaf(hk, ws[k], uacc);
        }
        tbf[(size_t)i * 64 + lane] = f2bf(tacc);
        u[(size_t)i * 64 + lane] = uacc;
    }
}

// ---------------- gather-aggregate + epilogue ----------------
// one wave per dst node; 4 edge-groups x 16 lanes; lane covers channels q*4..q*4+3.
// 32 edges per iteration: 8 independent uint2 loads -> 8 independent accumulators (MLP=8).
__global__ __launch_bounds__(256) void agg_kernel(const unsigned short* __restrict__ tbf,
                                                  const float* __restrict__ u,
                                                  const int2* __restrict__ row_info,
                                                  const unsigned short* __restrict__ csr,
                                                  float* __restrict__ out, int n, int use_mean) {
    int lane = threadIdx.x & 63;
    int g = lane >> 4;          // edge subgroup 0..3
    int q = lane & 15;          // channel quad
    int node = (blockIdx.x * 256 + threadIdx.x) >> 6;
    if (node >= n) return;
    int2 ri = row_info[node];
    int start = ri.x, deg = ri.y;
    float4 a0 = {0,0,0,0}, a1 = {0,0,0,0}, a2 = {0,0,0,0}, a3 = {0,0,0,0};
    float4 a4 = {0,0,0,0}, a5 = {0,0,0,0}, a6 = {0,0,0,0}, a7 = {0,0,0,0};
    for (int e = 0; e < deg; e += 64) {
        int cnt = deg - e;
        if (cnt > 64) cnt = 64;
        int idx = (lane < cnt) ? (int)csr[start + e + lane] : n;   // n -> zero row (L1-hot)
        int cnt32 = (cnt + 31) & ~31;
        for (int j = 0; j < cnt32; j += 32) {
            int s0 = __shfl(idx, j + g);
            int s1 = __shfl(idx, j + 4 + g);
            int s2 = __shfl(idx, j + 8 + g);
            int s3 = __shfl(idx, j + 12 + g);
            int s4 = __shfl(idx, j + 16 + g);
            int s5 = __shfl(idx, j + 20 + g);
            int s6 = __shfl(idx, j + 24 + g);
            int s7 = __shfl(idx, j + 28 + g);
            const uint2 w0 = *(const uint2*)(tbf + (size_t)s0 * 64 + q * 4);
            const uint2 w1 = *(const uint2*)(tbf + (size_t)s1 * 64 + q * 4);
            const uint2 w2 = *(const uint2*)(tbf + (size_t)s2 * 64 + q * 4);
            const uint2 w3 = *(const uint2*)(tbf + (size_t)s3 * 64 + q * 4);
            const uint2 w4 = *(const uint2*)(tbf + (size_t)s4 * 64 + q * 4);
            const uint2 w5 = *(const uint2*)(tbf + (size_t)s5 * 64 + q * 4);
            const uint2 w6 = *(const uint2*)(tbf + (size_t)s6 * 64 + q * 4);
            const uint2 w7 = *(const uint2*)(tbf + (size_t)s7 * 64 + q * 4);
            a0.x += bfl(w0.x); a0.y += bfh(w0.x); a0.z += bfl(w0.y); a0.w += bfh(w0.y);
            a1.x += bfl(w1.x); a1.y += bfh(w1.x); a1.z += bfl(w1.y); a1.w += bfh(w1.y);
            a2.x += bfl(w2.x); a2.y += bfh(w2.x); a2.z += bfl(w2.y); a2.w += bfh(w2.y);
            a3.x += bfl(w3.x); a3.y += bfh(w3.x); a3.z += bfl(w3.y); a3.w += bfh(w3.y);
            a4.x += bfl(w4.x); a4.y += bfh(w4.x); a4.z += bfl(w4.y); a4.w += bfh(w4.y);
            a5.x += bfl(w5.x); a5.y += bfh(w5.x); a5.z += bfl(w5.y); a5.w += bfh(w5.y);
            a6.x += bfl(w6.x); a6.y += bfh(w6.x); a6.z += bfl(w6.y); a6.w += bfh(w6.y);
            a7.x += bfl(w7.x); a7.y += bfh(w7.x); a7.z += bfl(w7.y); a7.w += bfh(w7.y);
        }
    }
    float4 acc;
    acc.x = ((a0.x + a1.x) + (a2.x + a3.x)) + ((a4.x + a5.x) + (a6.x + a7.x));
    acc.y = ((a0.y + a1.y) + (a2.y + a3.y)) + ((a4.y + a5.y) + (a6.y + a7.y));
    acc.z = ((a0.z + a1.z) + (a2.z + a3.z)) + ((a4.z + a5.z) + (a6.z + a7.z));
    acc.w = ((a0.w + a1.w) + (a2.w + a3.w)) + ((a4.w + a5.w) + (a6.w + a7.w));
    // reduce across the 4 edge-groups
    acc.x += __shfl_xor(acc.x, 16); acc.y += __shfl_xor(acc.y, 16);
    acc.z += __shfl_xor(acc.z, 16); acc.w += __shfl_xor(acc.w, 16);
    acc.x += __shfl_xor(acc.x, 32); acc.y += __shfl_xor(acc.y, 32);
    acc.z += __shfl_xor(acc.z, 32); acc.w += __shfl_xor(acc.w, 32);

    float scale = 1.f;
    if (use_mean) scale = 1.f / fmaxf((float)deg, 1.f);
    if (g == 0) {
        const float4 uv = *(const float4*)(u + (size_t)node * 64 + q * 4);
        float4 r;
        r.x = fmaxf(uv.x + acc.x * scale, 0.f);
        r.y = fmaxf(uv.y + acc.y * scale, 0.f);
        r.z = fmaxf(uv.z + acc.z * scale, 0.f);
        r.w = fmaxf(uv.w + acc.w * scale, 0.f);
        *(float4*)(out + (size_t)node * 64 + q * 4) = r;
    }
}

// ---------------- launch ----------------

extern "C" void kernel_launch(void* const* d_in, const int* in_sizes, int n_in,
                              void* d_out, int out_size, void* d_ws, size_t ws_size,
                              hipStream_t stream) {
    const float* x      = (const float*)d_in[0];
    const int*   ei     = (const int*)d_in[1];   // [2, E] int32
    const float* Wrel1  = (const float*)d_in[2];
    const float* Wroot1 = (const float*)d_in[3];
    const float* b1     = (const float*)d_in[4];
    const float* Wself2 = (const float*)d_in[5];
    const float* Wnbr2  = (const float*)d_in[6];
    const float* b2     = (const float*)d_in[7];
    const float* Wself3 = (const float*)d_in[8];
    const float* Wnbr3  = (const float*)d_in[9];
    const float* b3     = (const float*)d_in[10];
    const float* Wself4 = (const float*)d_in[11];
    const float* Wnbr4  = (const float*)d_in[12];
    const float* b4     = (const float*)d_in[13];

    const int N = N_NODES, E = N_EDGES;

    auto align = [](size_t o) { return (o + 255) & ~(size_t)255; };
    char* base = (char*)d_ws;
    size_t off = 0;
    int*  cursor   = (int*)(base + off);  off = align(off + (size_t)NBUK * 4);
    int2* row_info = (int2*)(base + off); off = align(off + (size_t)N_NODES * 8);
    int*  tmp      = (int*)(base + off);  off = align(off + (size_t)NBUK * PAD2 * 4);
    unsigned short* csr = (unsigned short*)(base + off); off = align(off + (size_t)NBUK * PAD2 * 2);
    unsigned short* tbf = (unsigned short*)(base + off); off = align(off + (size_t)(N + 1) * 64 * 2);
    float* u  = (float*)(base + off); off = align(off + (size_t)N * 64 * 4);
    float* h1 = (float*)(base + off); off = align(off + (size_t)N * 64 * 4);

    float* out1 = (float*)d_out;                      // x_1
    float* out2 = (float*)d_out + (size_t)N * 64;     // x_2

    // ---- CSR build: 3 dispatches ----
    init_kernel<<<1, 512, 0, stream>>>(cursor);
    scatter_fused_kernel<<<GBIN, 256, 0, stream>>>(ei, cursor, tmp, E);
    bucketize_kernel<<<NBUK, 512, 0, stream>>>(tmp, cursor, row_info, csr, N);

    const int GB = 768;            // gemm blocks (3072 waves)
    const int AB = (N + 3) / 4;    // 12500 blocks = 50000 waves

    // Layer 1 (RGCN): u = x@W_root1 + b1 ; t = x@W_rel1 ; mean aggregate
    gemm2_kernel<<<GB, 256, 0, stream>>>(x, Wrel1, Wroot1, b1, tbf, u, N);
    agg_kernel<<<AB, 256, 0, stream>>>(tbf, u, row_info, csr, h1, N, 1);
    // Layer 2 (GraphConv) -> x_1
    gemm2_kernel<<<GB, 256, 0, stream>>>(h1, Wnbr2, Wself2, b2, tbf, u, N);
    agg_kernel<<<AB, 256, 0, stream>>>(tbf, u, row_info, csr, out1, N, 0);
    // Layer 3
    gemm2_kernel<<<GB, 256, 0, stream>>>(out1, Wnbr3, Wself3, b3, tbf, u, N);
    agg_kernel<<<AB, 256, 0, stream>>>(tbf, u, row_info, csr, h1, N, 0);
    // Layer 4 -> x_2
    gemm2_kernel<<<GB, 256, 0, stream>>>(h1, Wnbr4, Wself4, b4, tbf, u, N);
    agg_kernel<<<AB, 256, 0, stream>>>(tbf, u, row_info, csr, out2, N, 0);
}